// Round 1
// 423.759 us; speedup vs baseline: 1.0552x; 1.0552x over previous
//
#include <hip/hip_runtime.h>
#include <hip/hip_bf16.h>

#define N_NODES  100000
#define N_EDGES  1600000
#define N_GRAPHS 256
#define DCH      128
#define DOUT     64
#define NB       391      // buckets = ceil(100000/256)
#define PADB     512
#define SLACK    4608     // per-bucket region capacity (mean 4096 + 8 sigma)
#define CHUNK    4096     // edges per binA block
#define PCH      64       // nodes per pool block

typedef short v8s __attribute__((ext_vector_type(8)));
typedef float v4f __attribute__((ext_vector_type(4)));

static __device__ __forceinline__ float bf2f(unsigned short u) {
    unsigned int x = ((unsigned int)u) << 16;
    return __builtin_bit_cast(float, x);
}
static __device__ __forceinline__ unsigned short f2bf(float f) {
    unsigned int x = __builtin_bit_cast(unsigned int, f);
    unsigned int r = (x + 0x7fffu + ((x >> 16) & 1u)) >> 16;
    return (unsigned short)r;
}
static __device__ __forceinline__ int clampi(int v, int lo, int hi) {
    return v < lo ? lo : (v > hi ? hi : v);
}

// ---------------- fp32 -> bf16 feature conversion ----------------
__global__ void cvt_kernel(const float* __restrict__ in, unsigned short* __restrict__ out) {
    size_t i = ((size_t)blockIdx.x * blockDim.x + threadIdx.x) * 4;
    if (i + 3 < (size_t)N_NODES * DCH) {
        float4 f = *reinterpret_cast<const float4*>(in + i);
        uint2 o;
        o.x = ((unsigned)f2bf(f.y) << 16) | (unsigned)f2bf(f.x);
        o.y = ((unsigned)f2bf(f.w) << 16) | (unsigned)f2bf(f.z);
        *reinterpret_cast<uint2*>(out + i) = o;
    }
}

// ---------------- edge binning pass A: partition edges into dst>>8 buckets ----------------
// gcur must be zero-initialized; bucket b's region base is b*SLACK.
__global__ void __launch_bounds__(256) binA_kernel(const int* __restrict__ src, const int* __restrict__ dst,
                                                   int* __restrict__ gcur, uint2* __restrict__ region) {
    __shared__ uint2 stage[CHUNK];          // 32 KB
    __shared__ int hcnt[PADB], hcnt2[PADB], hoff[PADB], garr[PADB];
    __shared__ int s2[256];
    int tid = threadIdx.x;
    int e0  = blockIdx.x * CHUNK;
    int nedge = N_EDGES - e0; if (nedge > CHUNK) nedge = CHUNK;

    for (int b = tid; b < PADB; b += 256) { hcnt[b] = 0; hcnt2[b] = 0; }
    __syncthreads();

    // phase 1: read edges into registers, LDS bucket histogram
    int es[16], ed[16];
    #pragma unroll
    for (int j = 0; j < 16; j++) {
        int e = e0 + j * 256 + tid;
        if (e < N_EDGES) {
            es[j] = clampi(src[e], 0, N_NODES - 1);
            ed[j] = clampi(dst[e], 0, N_NODES - 1);
            atomicAdd(&hcnt[ed[j] >> 8], 1);
        } else { es[j] = -1; ed[j] = 0; }
    }
    __syncthreads();

    // phase 2a: exclusive scan of hcnt[512] -> hoff
    int v0 = hcnt[2 * tid], v1 = hcnt[2 * tid + 1];
    s2[tid] = v0 + v1; __syncthreads();
    for (int off = 1; off < 256; off <<= 1) {
        int x = (tid >= off) ? s2[tid - off] : 0;
        __syncthreads();
        s2[tid] += x;
        __syncthreads();
    }
    int excl = s2[tid] - (v0 + v1);
    hoff[2 * tid] = excl; hoff[2 * tid + 1] = excl + v0;
    __syncthreads();

    // phase 2b: reserve global bucket space (gcur holds counts; base b*SLACK added here)
    for (int b = tid; b < NB; b += 256) {
        int c = hcnt[b];
        garr[b] = b * SLACK + ((c > 0) ? atomicAdd(&gcur[b], c) : 0);
    }
    __syncthreads();

    // phase 3: place edges into stage, bucket-contiguous
    #pragma unroll
    for (int j = 0; j < 16; j++) {
        if (es[j] >= 0) {
            int b = ed[j] >> 8;
            int pos = atomicAdd(&hcnt2[b], 1) + hoff[b];
            stage[pos] = (uint2){(unsigned)es[j], (unsigned)ed[j]};
        }
    }
    __syncthreads();

    // phase 4: coalesced-ish write of bucket runs to global region
    for (int i = tid; i < nedge; i += 256) {
        uint2 en = stage[i];
        int b = (int)(en.y >> 8);
        int gpos = garr[b] + (i - hoff[b]);
        if (gpos < (b + 1) * SLACK) region[gpos] = en;   // overflow guard (prob ~0)
    }
}

// ---------------- binFinish: per-bucket degree + rowptr + csr scatter (fused) ----------------
__global__ void __launch_bounds__(256) binFinish_kernel(const uint2* __restrict__ region, const int* __restrict__ gcur,
                                                        int* __restrict__ rowptr, int* __restrict__ csr) {
    __shared__ int h[256], sc[256], cur[256], s2[256], hoff[PADB];
    int b = blockIdx.x, tid = threadIdx.x;
    // 1. global bucket prefix (all blocks redundantly; gcur entries >= NB are 0)
    int c0 = gcur[2 * tid];     if (c0 > SLACK) c0 = SLACK;
    int c1 = gcur[2 * tid + 1]; if (c1 > SLACK) c1 = SLACK;
    s2[tid] = c0 + c1;
    h[tid] = 0;
    __syncthreads();
    for (int off = 1; off < 256; off <<= 1) {
        int x = (tid >= off) ? s2[tid - off] : 0;
        __syncthreads();
        s2[tid] += x;
        __syncthreads();
    }
    int excl = s2[tid] - (c0 + c1);
    hoff[2 * tid] = excl; hoff[2 * tid + 1] = excl + c0;
    __syncthreads();
    if (b == 0 && tid == 255) rowptr[N_NODES] = hoff[511];  // buckets NB..510 are 0-size
    int base = hoff[b];
    int size = gcur[b]; if (size > SLACK) size = SLACK;
    int node0 = b * 256;
    // 2. degree histogram
    for (int j = tid; j < size; j += 256) {
        unsigned loc = region[b * SLACK + j].y - (unsigned)node0;
        if (loc < 256u) atomicAdd(&h[loc], 1);
    }
    __syncthreads();
    // 3. local scan -> rowptr + cursors
    int v = h[tid]; sc[tid] = v; __syncthreads();
    for (int off = 1; off < 256; off <<= 1) {
        int x = (tid >= off) ? sc[tid - off] : 0;
        __syncthreads();
        sc[tid] += x;
        __syncthreads();
    }
    int myptr = base + sc[tid] - v;
    int node = node0 + tid;
    if (node < N_NODES) rowptr[node] = myptr;
    cur[tid] = myptr;
    __syncthreads();
    // 4. scatter into csr
    for (int j = tid; j < size; j += 256) {
        uint2 en = region[b * SLACK + j];
        unsigned loc = en.y - (unsigned)node0;
        if (loc < 256u) {
            int p = atomicAdd(&cur[loc], 1);
            if (p >= 0 && p < N_EDGES) csr[p] = (int)en.x;
        }
    }
}

// ---------------- weight fragment pre-swizzle (fp32 -> bf16) ----------------
// B [256x128] = [Wrel; Wroot]; mfma_f32_16x16x32_bf16 B-layout:
// lane holds B[k = kt*32 + (lane>>4)*8 + j][n = nt*16 + (lane&15)]
__global__ void wfrag_kernel(const float* __restrict__ W1rel, const float* __restrict__ W1root,
                             const float* __restrict__ W2rel, const float* __restrict__ W2root,
                             const float* __restrict__ W3rel, const float* __restrict__ W3root,
                             unsigned short* __restrict__ frag) {
    int gid = blockIdx.x * blockDim.x + threadIdx.x;
    if (gid >= 3 * 8 * 8 * 64) return;
    int lane = gid & 63;
    int nt   = (gid >> 6) & 7;
    int kt   = (gid >> 9) & 7;
    int L    = gid >> 12;
    const float* rel  = (L == 0) ? W1rel  : (L == 1) ? W2rel  : W3rel;
    const float* root = (L == 0) ? W1root : (L == 1) ? W2root : W3root;
    int n  = nt * 16 + (lane & 15);
    int k0 = kt * 32 + (lane >> 4) * 8;
    unsigned short o[8];
    #pragma unroll
    for (int j = 0; j < 8; j++) {
        int k = k0 + j;
        float w = (k < 128) ? rel[k * 128 + n] : root[(k - 128) * 128 + n];
        o[j] = f2bf(w);
    }
    uint4 u;
    u.x = (unsigned)o[0] | ((unsigned)o[1] << 16);
    u.y = (unsigned)o[2] | ((unsigned)o[3] << 16);
    u.z = (unsigned)o[4] | ((unsigned)o[5] << 16);
    u.w = (unsigned)o[6] | ((unsigned)o[7] << 16);
    *reinterpret_cast<uint4*>(frag + (size_t)gid * 8) = u;
}

// ---------------- fused layer: agg (mean gather) + GEMM + bias + relu ----------------
// One wave per 32 output rows; grid = N_NODES/32 = 3125 exactly (no tail).
// Agg phase: per node, 16-wide index fetch + 16 unconditional saddr gathers.
//   - readlane puts the row index in an SGPR -> scalar address math (SALU pipe),
//     saddr-form global_load_dword: ~5 VALU slots/edge vs ~9 in the old agg.
//   - padded lanes gather the all-zero row N_NODES (no per-j weight cndmask).
// Agg rows land in wave-private LDS (8 KB), XOR-swizzled (byte ^= (row&7)<<4) so the
// MFMA-phase ds_read_b128 A-fragment reads are conflict-free (8 lanes/bank-group = b128 min).
// MFMA phase: kt 0-3 A from LDS (agg half), kt 4-7 A from global root rows (contiguous).
// hin != hout (ping-pong buffers) -> no cross-block race on the gather source.
__global__ void __launch_bounds__(64, 4) layer_kernel(
    const unsigned short* __restrict__ hin,   // N_NODES+1 rows; row N_NODES is zero
    const int* __restrict__ rowptr, const int* __restrict__ csr,
    const unsigned short* __restrict__ frag, const float* __restrict__ bias,
    unsigned short* __restrict__ hout, int relu)
{
    __shared__ __attribute__((aligned(16))) unsigned short As[32 * DCH];  // 8 KB
    const int lane = threadIdx.x & 63;
    const int l16  = lane & 15;
    const int quad = lane >> 4;
    const int base = blockIdx.x * 32;

    // rowptr[base .. base+32]: one coalesced load, then readlane per node
    int rp = rowptr[base + (lane < 33 ? lane : 32)];

    char* Asb = reinterpret_cast<char*>(As);

    // ---------- aggregation: 32 nodes ----------
    for (int i = 0; i < 32; i++) {
        int r0 = __builtin_amdgcn_readlane(rp, i);
        int r1 = __builtin_amdgcn_readlane(rp, i + 1);
        float a0 = 0.f, a1 = 0.f;
        for (int c = r0; c < r1; c += 16) {
            int e = c + l16;
            int idx = (e < r1) ? csr[e] : N_NODES;   // zero-row padding (csr is over-allocated +16)
            #pragma unroll
            for (int j = 0; j < 16; j++) {
                int s = __builtin_amdgcn_readlane(idx, j);   // SGPR -> saddr gather
                unsigned v = *reinterpret_cast<const unsigned*>(hin + (size_t)s * DCH + lane * 2);
                a0 += bf2f((unsigned short)(v & 0xffffu));
                a1 += bf2f((unsigned short)(v >> 16));
            }
        }
        int deg = r1 - r0;
        float inv = 1.0f / (float)(deg > 1 ? deg : 1);
        unsigned o = ((unsigned)f2bf(a1 * inv) << 16) | (unsigned)f2bf(a0 * inv);
        // swizzled wave-private LDS write (conflict-free: bank permutation per row)
        *reinterpret_cast<unsigned*>(Asb + i * 256 + ((lane * 4) ^ ((i & 7) << 4))) = o;
    }
    // Single wave per block: LDS region is wave-private; compiler-inserted lgkmcnt
    // ordering covers the write->read dependency. No barrier needed.

    // ---------- MFMA: [agg | root] @ [Wrel; Wroot] ----------
    v4f acc[2][8];
    #pragma unroll
    for (int h = 0; h < 2; h++)
        #pragma unroll
        for (int nt = 0; nt < 8; nt++) acc[h][nt] = (v4f){0.f, 0.f, 0.f, 0.f};

    #pragma unroll
    for (int kt = 0; kt < 8; kt++) {
        v8s a0v, a1v;
        if (kt < 4) {
            // A from swizzled LDS: row = (h*16)+l16, byte col = kt*64 + quad*16
            int co = (kt * 64 + quad * 16) ^ ((l16 & 7) << 4);
            a0v = *reinterpret_cast<const v8s*>(Asb + l16 * 256 + co);
            a1v = *reinterpret_cast<const v8s*>(Asb + (16 + l16) * 256 + co);
        } else {
            // A from global root rows (contiguous, coalesced)
            int ak = (kt - 4) * 32 + quad * 8;
            a0v = *reinterpret_cast<const v8s*>(hin + (size_t)(base + l16) * DCH + ak);
            a1v = *reinterpret_cast<const v8s*>(hin + (size_t)(base + 16 + l16) * DCH + ak);
        }
        #pragma unroll
        for (int nt = 0; nt < 8; nt++) {
            v8s b = *reinterpret_cast<const v8s*>(frag + (((size_t)(kt * 8 + nt)) * 64 + lane) * 8);
            acc[0][nt] = __builtin_amdgcn_mfma_f32_16x16x32_bf16(a0v, b, acc[0][nt], 0, 0, 0);
            acc[1][nt] = __builtin_amdgcn_mfma_f32_16x16x32_bf16(a1v, b, acc[1][nt], 0, 0, 0);
        }
    }
    #pragma unroll
    for (int h = 0; h < 2; h++) {
        int mbase = base + h * 16 + quad * 4;
        #pragma unroll
        for (int nt = 0; nt < 8; nt++) {
            int n = nt * 16 + l16;
            float bv = bias[n];
            #pragma unroll
            for (int r = 0; r < 4; r++) {
                float v = acc[h][nt][r] + bv;
                if (relu) v = fmaxf(v, 0.f);
                hout[(size_t)(mbase + r) * DCH + n] = f2bf(v);
            }
        }
    }
}

// ---------------- pooling stage 1: segmented sum into psum (batch sorted) ----------------
__global__ void __launch_bounds__(128) pool_kernel(const unsigned short* __restrict__ h,
                                                   const int* __restrict__ batch,
                                                   float* __restrict__ psum) {
    int c  = threadIdx.x; // 0..127
    int n0 = blockIdx.x * PCH;
    int n1 = n0 + PCH < N_NODES ? n0 + PCH : N_NODES;
    if (n0 >= n1) return;
    int cur = clampi(batch[n0], 0, N_GRAPHS - 1);
    float acc = 0.f;
    for (int n = n0; n < n1; n++) {
        int g = clampi(batch[n], 0, N_GRAPHS - 1);
        if (g != cur) {
            atomicAdd(&psum[cur * DCH + c], acc);
            acc = 0.f; cur = g;
        }
        acc += bf2f(h[(size_t)n * DCH + c]);
    }
    atomicAdd(&psum[cur * DCH + c], acc);
}

// ---------------- pooling stage 2: out[g] = (psum[g]/cnt_g) @ Wl + bl ----------------
static __device__ __forceinline__ int lowerb(const int* __restrict__ a, int n, int key) {
    int lo = 0, hi = n;
    while (lo < hi) { int mid = (lo + hi) >> 1; if (a[mid] < key) lo = mid + 1; else hi = mid; }
    return lo;
}

__global__ void __launch_bounds__(64) final_kernel(const float* __restrict__ psum,
                                                   const int* __restrict__ batch,
                                                   const float* __restrict__ Wl, const float* __restrict__ bl,
                                                   float* __restrict__ out) {
    __shared__ float ps[DCH];
    __shared__ int bounds[2];
    int g = blockIdx.x, tid = threadIdx.x;
    if (tid == 0) {
        bounds[0] = lowerb(batch, N_NODES, g);
        bounds[1] = lowerb(batch, N_NODES, g + 1);
    }
    __syncthreads();
    int cnt = bounds[1] - bounds[0];
    float inv = 1.0f / (float)(cnt > 1 ? cnt : 1);
    ps[tid] = psum[g * DCH + tid] * inv;
    ps[tid + 64] = psum[g * DCH + tid + 64] * inv;
    __syncthreads();
    float o = 0.f;
    #pragma unroll 4
    for (int c = 0; c < DCH; c++) o += ps[c] * Wl[c * DOUT + tid];
    out[g * DOUT + tid] = o + bl[tid];
}

extern "C" void kernel_launch(void* const* d_in, const int* in_sizes, int n_in,
                              void* d_out, int out_size, void* d_ws, size_t ws_size,
                              hipStream_t stream) {
    const float* x     = (const float*)d_in[0];
    const int*   edge  = (const int*)d_in[1];
    const int*   src   = edge;
    const int*   dst   = edge + N_EDGES;
    const int*   batch = (const int*)d_in[2];
    const float* W1rel  = (const float*)d_in[3];
    const float* b1     = (const float*)d_in[4];
    const float* W1root = (const float*)d_in[5];
    const float* W2rel  = (const float*)d_in[6];
    const float* b2     = (const float*)d_in[7];
    const float* W2root = (const float*)d_in[8];
    const float* W3rel  = (const float*)d_in[9];
    const float* b3     = (const float*)d_in[10];
    const float* W3root = (const float*)d_in[11];
    const float* Wl     = (const float*)d_in[12];
    const float* bl     = (const float*)d_in[13];
    float* out = (float*)d_out;

    char* ws = (char*)d_ws;
    size_t off = 0;
    auto carve = [&](size_t bytes) -> void* {
        void* p = ws + off;
        off += (bytes + 255) & ~(size_t)255;
        return p;
    };
    // ~58.3 MiB total; bucket region reuses B1 (free during CSR build)
    int*            rowptr  = (int*)carve((size_t)(N_NODES + 1) * 4);
    int*            csr     = (int*)carve((size_t)(N_EDGES + 16) * 4);   // +16: padded reads in layer_kernel
    int*            gcur    = (int*)carve((size_t)PADB * 4 + (size_t)N_GRAPHS * DCH * 4); // gcur + psum, one memset
    float*          psum    = (float*)(gcur + PADB);
    unsigned short* frag    = (unsigned short*)carve((size_t)3 * 8 * 8 * 64 * 8 * 2);
    unsigned short* B1      = (unsigned short*)carve((size_t)(N_NODES + 1) * DCH * 2);   // +1 zero row
    unsigned short* B2      = (unsigned short*)carve((size_t)(N_NODES + 1) * DCH * 2);   // +1 zero row
    uint2*          region  = (uint2*)B1;   // 391*4608*8 = 14.4 MB <= 25.6 MB (zero row is beyond region)

    hipMemsetAsync(gcur, 0, (size_t)PADB * 4 + (size_t)N_GRAPHS * DCH * 4, stream);
    // zero rows (gather target for padded lanes); never overwritten by any kernel
    hipMemsetAsync(B1 + (size_t)N_NODES * DCH, 0, (size_t)DCH * 2, stream);
    hipMemsetAsync(B2 + (size_t)N_NODES * DCH, 0, (size_t)DCH * 2, stream);

    // CSR build: binA -> binFinish
    binA_kernel<<<(N_EDGES + CHUNK - 1) / CHUNK, 256, 0, stream>>>(src, dst, gcur, region);
    binFinish_kernel<<<NB, 256, 0, stream>>>(region, gcur, rowptr, csr);
    // features + weights
    cvt_kernel<<<(N_NODES * DCH / 4 + 255) / 256, 256, 0, stream>>>(x, B2);
    wfrag_kernel<<<(3 * 8 * 8 * 64 + 255) / 256, 256, 0, stream>>>(W1rel, W1root, W2rel, W2root, W3rel, W3root, frag);

    const int layerGrid = N_NODES / 32;   // 3125, exact

    // fused layers (agg + gemm + bias + relu); ping-pong B2 -> B1 -> B2 -> B1
    layer_kernel<<<layerGrid, 64, 0, stream>>>(B2, rowptr, csr, frag,         b1, B1, 1);
    layer_kernel<<<layerGrid, 64, 0, stream>>>(B1, rowptr, csr, frag + 32768, b2, B2, 1);
    layer_kernel<<<layerGrid, 64, 0, stream>>>(B2, rowptr, csr, frag + 65536, b3, B1, 0);

    // pooling: wide segmented sum, then per-graph matvec
    pool_kernel<<<(N_NODES + PCH - 1) / PCH, 128, 0, stream>>>(B1, batch, psum);
    final_kernel<<<N_GRAPHS, 64, 0, stream>>>(psum, batch, Wl, bl, out);
}

// Round 2
// 414.879 us; speedup vs baseline: 1.0777x; 1.0214x over previous
//
#include <hip/hip_runtime.h>
#include <hip/hip_bf16.h>

#define N_NODES  100000
#define N_EDGES  1600000
#define N_GRAPHS 256
#define DCH      128
#define DOUT     64
#define NB       391      // buckets = ceil(100000/256)
#define PADB     512
#define SLACK    4608     // per-bucket region capacity (mean 4096 + 8 sigma)
#define CHUNK    2048     // edges per binA block (391 -> 782 blocks: occupancy)
#define PCH      32       // nodes per pool block

typedef short v8s __attribute__((ext_vector_type(8)));
typedef float v4f __attribute__((ext_vector_type(4)));

static __device__ __forceinline__ float bf2f(unsigned short u) {
    unsigned int x = ((unsigned int)u) << 16;
    return __builtin_bit_cast(float, x);
}
static __device__ __forceinline__ unsigned short f2bf(float f) {
    unsigned int x = __builtin_bit_cast(unsigned int, f);
    unsigned int r = (x + 0x7fffu + ((x >> 16) & 1u)) >> 16;
    return (unsigned short)r;
}
static __device__ __forceinline__ int clampi(int v, int lo, int hi) {
    return v < lo ? lo : (v > hi ? hi : v);
}

// ---------------- fp32 -> bf16 feature conversion ----------------
__global__ void cvt_kernel(const float* __restrict__ in, unsigned short* __restrict__ out) {
    size_t i = ((size_t)blockIdx.x * blockDim.x + threadIdx.x) * 4;
    if (i + 3 < (size_t)N_NODES * DCH) {
        float4 f = *reinterpret_cast<const float4*>(in + i);
        uint2 o;
        o.x = ((unsigned)f2bf(f.y) << 16) | (unsigned)f2bf(f.x);
        o.y = ((unsigned)f2bf(f.w) << 16) | (unsigned)f2bf(f.z);
        *reinterpret_cast<uint2*>(out + i) = o;
    }
}

// ---------------- edge binning pass A: partition edges into dst>>8 buckets ----------------
// gcur must be zero-initialized; bucket b's region base is b*SLACK.
__global__ void __launch_bounds__(256) binA_kernel(const int* __restrict__ src, const int* __restrict__ dst,
                                                   int* __restrict__ gcur, uint2* __restrict__ region) {
    __shared__ uint2 stage[CHUNK];          // 16 KB
    __shared__ int hcnt[PADB], hcnt2[PADB], hoff[PADB], garr[PADB];
    __shared__ int s2[256];
    int tid = threadIdx.x;
    int e0  = blockIdx.x * CHUNK;
    int nedge = N_EDGES - e0; if (nedge > CHUNK) nedge = CHUNK;

    for (int b = tid; b < PADB; b += 256) { hcnt[b] = 0; hcnt2[b] = 0; }
    __syncthreads();

    // phase 1: read edges into registers, LDS bucket histogram
    int es[CHUNK / 256], ed[CHUNK / 256];
    #pragma unroll
    for (int j = 0; j < CHUNK / 256; j++) {
        int e = e0 + j * 256 + tid;
        if (e < N_EDGES) {
            es[j] = clampi(src[e], 0, N_NODES - 1);
            ed[j] = clampi(dst[e], 0, N_NODES - 1);
            atomicAdd(&hcnt[ed[j] >> 8], 1);
        } else { es[j] = -1; ed[j] = 0; }
    }
    __syncthreads();

    // phase 2a: exclusive scan of hcnt[512] -> hoff
    int v0 = hcnt[2 * tid], v1 = hcnt[2 * tid + 1];
    s2[tid] = v0 + v1; __syncthreads();
    for (int off = 1; off < 256; off <<= 1) {
        int x = (tid >= off) ? s2[tid - off] : 0;
        __syncthreads();
        s2[tid] += x;
        __syncthreads();
    }
    int excl = s2[tid] - (v0 + v1);
    hoff[2 * tid] = excl; hoff[2 * tid + 1] = excl + v0;
    __syncthreads();

    // phase 2b: reserve global bucket space (gcur holds counts; base b*SLACK added here)
    for (int b = tid; b < NB; b += 256) {
        int c = hcnt[b];
        garr[b] = b * SLACK + ((c > 0) ? atomicAdd(&gcur[b], c) : 0);
    }
    __syncthreads();

    // phase 3: place edges into stage, bucket-contiguous
    #pragma unroll
    for (int j = 0; j < CHUNK / 256; j++) {
        if (es[j] >= 0) {
            int b = ed[j] >> 8;
            int pos = atomicAdd(&hcnt2[b], 1) + hoff[b];
            stage[pos] = (uint2){(unsigned)es[j], (unsigned)ed[j]};
        }
    }
    __syncthreads();

    // phase 4: coalesced-ish write of bucket runs to global region
    for (int i = tid; i < nedge; i += 256) {
        uint2 en = stage[i];
        int b = (int)(en.y >> 8);
        int gpos = garr[b] + (i - hoff[b]);
        if (gpos < (b + 1) * SLACK) region[gpos] = en;   // overflow guard (prob ~0)
    }
}

// ---------------- scan: global bucket prefix (once, instead of 391x in binFinish) ----------------
__global__ void __launch_bounds__(256) scan_kernel(const int* __restrict__ gcur,
                                                   int* __restrict__ hoffG, int* __restrict__ rowptr) {
    __shared__ int s2[256];
    int tid = threadIdx.x;
    int c0 = gcur[2 * tid];     if (c0 > SLACK) c0 = SLACK;
    int c1 = gcur[2 * tid + 1]; if (c1 > SLACK) c1 = SLACK;
    s2[tid] = c0 + c1; __syncthreads();
    for (int off = 1; off < 256; off <<= 1) {
        int x = (tid >= off) ? s2[tid - off] : 0;
        __syncthreads();
        s2[tid] += x;
        __syncthreads();
    }
    int excl = s2[tid] - (c0 + c1);
    hoffG[2 * tid] = excl; hoffG[2 * tid + 1] = excl + c0;
    if (tid == 255) rowptr[N_NODES] = s2[255];
}

// ---------------- binFinish: per-bucket degree + rowptr + csr scatter ----------------
__global__ void __launch_bounds__(256) binFinish_kernel(const uint2* __restrict__ region, const int* __restrict__ gcur,
                                                        const int* __restrict__ hoffG,
                                                        int* __restrict__ rowptr, int* __restrict__ csr) {
    __shared__ int h[256], sc[256], cur[256];
    int b = blockIdx.x, tid = threadIdx.x;
    h[tid] = 0;
    int base = hoffG[b];
    int size = gcur[b]; if (size > SLACK) size = SLACK;
    int node0 = b * 256;
    __syncthreads();
    // 1. degree histogram
    for (int j = tid; j < size; j += 256) {
        unsigned loc = region[b * SLACK + j].y - (unsigned)node0;
        if (loc < 256u) atomicAdd(&h[loc], 1);
    }
    __syncthreads();
    // 2. local scan -> rowptr + cursors
    int v = h[tid]; sc[tid] = v; __syncthreads();
    for (int off = 1; off < 256; off <<= 1) {
        int x = (tid >= off) ? sc[tid - off] : 0;
        __syncthreads();
        sc[tid] += x;
        __syncthreads();
    }
    int myptr = base + sc[tid] - v;
    int node = node0 + tid;
    if (node < N_NODES) rowptr[node] = myptr;
    cur[tid] = myptr;
    __syncthreads();
    // 3. scatter into csr
    for (int j = tid; j < size; j += 256) {
        uint2 en = region[b * SLACK + j];
        unsigned loc = en.y - (unsigned)node0;
        if (loc < 256u) {
            int p = atomicAdd(&cur[loc], 1);
            if (p >= 0 && p < N_EDGES) csr[p] = (int)en.x;
        }
    }
}

// ---------------- weight fragment pre-swizzle (fp32 -> bf16) ----------------
// B [256x128] = [Wrel; Wroot]; mfma_f32_16x16x32_bf16 B-layout:
// lane holds B[k = kt*32 + (lane>>4)*8 + j][n = nt*16 + (lane&15)]
__global__ void wfrag_kernel(const float* __restrict__ W1rel, const float* __restrict__ W1root,
                             const float* __restrict__ W2rel, const float* __restrict__ W2root,
                             const float* __restrict__ W3rel, const float* __restrict__ W3root,
                             unsigned short* __restrict__ frag) {
    int gid = blockIdx.x * blockDim.x + threadIdx.x;
    if (gid >= 3 * 8 * 8 * 64) return;
    int lane = gid & 63;
    int nt   = (gid >> 6) & 7;
    int kt   = (gid >> 9) & 7;
    int L    = gid >> 12;
    const float* rel  = (L == 0) ? W1rel  : (L == 1) ? W2rel  : W3rel;
    const float* root = (L == 0) ? W1root : (L == 1) ? W2root : W3root;
    int n  = nt * 16 + (lane & 15);
    int k0 = kt * 32 + (lane >> 4) * 8;
    unsigned short o[8];
    #pragma unroll
    for (int j = 0; j < 8; j++) {
        int k = k0 + j;
        float w = (k < 128) ? rel[k * 128 + n] : root[(k - 128) * 128 + n];
        o[j] = f2bf(w);
    }
    uint4 u;
    u.x = (unsigned)o[0] | ((unsigned)o[1] << 16);
    u.y = (unsigned)o[2] | ((unsigned)o[3] << 16);
    u.z = (unsigned)o[4] | ((unsigned)o[5] << 16);
    u.w = (unsigned)o[6] | ((unsigned)o[7] << 16);
    *reinterpret_cast<uint4*>(frag + (size_t)gid * 8) = u;
}

// ---------------- fused layer: agg (mean gather) + GEMM + bias + relu ----------------
// 128-thread blocks, 2 waves; each wave owns 32 output rows + a private 8 KB LDS half
// (no barriers). Grid = ceil(100000/64) = 1563.
// Agg phase = FLAT EDGE STREAM over the wave's [rp[0], rp[32]) range in 16-edge chunks:
//   - next csr chunk prefetched one iteration ahead (hides index-load latency),
//   - all 16 gathers batch-issued into v[16] with no control flow between them
//     (one vmcnt window, saddr-form loads via readlane -> SGPR row index),
//   - node boundaries handled on the scalar pipe (e == nend compare + cascade
//     finalize); padded lanes gather the all-zero row N_NODES and add 0.
// This removes the per-node csr-load stall of the previous version (~1 uncovered
// latency per node) and raises occupancy 9 -> ~20 waves/CU.
__global__ void __launch_bounds__(128, 4) layer_kernel(
    const unsigned short* __restrict__ hin,   // N_NODES+1 rows; row N_NODES is zero
    const int* __restrict__ rowptr, const int* __restrict__ csr,
    const unsigned short* __restrict__ frag, const float* __restrict__ bias,
    unsigned short* __restrict__ hout, int relu)
{
    __shared__ __attribute__((aligned(16))) unsigned short As[2][32 * DCH];  // 16 KB
    const int wave = threadIdx.x >> 6;
    const int lane = threadIdx.x & 63;
    const int l16  = lane & 15;
    const int quad = lane >> 4;
    const int base = blockIdx.x * 64 + wave * 32;
    if (base >= N_NODES) return;

    char* Asb = reinterpret_cast<char*>(As[wave]);

    // rowptr[base .. base+32]: one coalesced load; readlane thereafter (SGPR)
    int rp = rowptr[base + (lane < 33 ? lane : 32)];
    const int R0 = __builtin_amdgcn_readlane(rp, 0);
    const int R1 = __builtin_amdgcn_readlane(rp, 32);

    int ni     = 0;                                   // current node (0..31), scalar
    int nstart = R0;
    int nend   = __builtin_amdgcn_readlane(rp, 1);
    float a0 = 0.f, a1 = 0.f;

    // first csr chunk (csr over-allocated +64 so unconditional loads are in-bounds)
    int t0  = csr[R0 + l16];
    int idx = (R0 + l16 < R1) ? t0 : N_NODES;

    for (int e0 = R0; e0 < R1; e0 += 16) {
        // prefetch next csr chunk
        int en   = e0 + 16 + l16;
        int tn   = csr[en];
        int idxn = (en < R1) ? tn : N_NODES;

        // batch-issue 16 independent gathers (all in one vmcnt window)
        unsigned v[16];
        #pragma unroll
        for (int j = 0; j < 16; j++) {
            int s = __builtin_amdgcn_readlane(idx, j);           // SGPR row index
            v[j] = *reinterpret_cast<const unsigned*>(hin + (size_t)s * DCH + lane * 2);
        }

        // process chunk: scalar-pipe boundary bookkeeping + VALU accumulate
        #pragma unroll
        for (int j = 0; j < 16; j++) {
            int e = e0 + j;                                      // uniform
            while (ni < 32 && e == nend) {                       // finalize node ni
                int deg = nend - nstart;
                float inv = 1.0f / (float)(deg > 1 ? deg : 1);
                unsigned o = ((unsigned)f2bf(a1 * inv) << 16) | (unsigned)f2bf(a0 * inv);
                *reinterpret_cast<unsigned*>(Asb + ni * 256 + ((lane * 4) ^ ((ni & 7) << 4))) = o;
                a0 = 0.f; a1 = 0.f;
                ni++;
                nstart = nend;
                nend = __builtin_amdgcn_readlane(rp, ni + 1);
            }
            a0 += bf2f((unsigned short)(v[j] & 0xffffu));        // padded edges add 0
            a1 += bf2f((unsigned short)(v[j] >> 16));
        }
        idx = idxn;
    }
    // finalize remaining nodes (stream ended on a chunk boundary, or zero-degree tail)
    while (ni < 32) {
        int deg = nend - nstart;
        float inv = 1.0f / (float)(deg > 1 ? deg : 1);
        unsigned o = ((unsigned)f2bf(a1 * inv) << 16) | (unsigned)f2bf(a0 * inv);
        *reinterpret_cast<unsigned*>(Asb + ni * 256 + ((lane * 4) ^ ((ni & 7) << 4))) = o;
        a0 = 0.f; a1 = 0.f;
        ni++;
        nstart = nend;
        nend = __builtin_amdgcn_readlane(rp, ni + 1 < 33 ? ni + 1 : 32);
    }
    // wave-private LDS: compiler-inserted lgkmcnt covers write->read dep; no barrier.

    // ---------- MFMA: [agg | root] @ [Wrel; Wroot] ----------
    v4f acc[2][8];
    #pragma unroll
    for (int h = 0; h < 2; h++)
        #pragma unroll
        for (int nt = 0; nt < 8; nt++) acc[h][nt] = (v4f){0.f, 0.f, 0.f, 0.f};

    #pragma unroll
    for (int kt = 0; kt < 8; kt++) {
        v8s a0v, a1v;
        if (kt < 4) {
            // A from swizzled LDS: row = (h*16)+l16, byte col = kt*64 + quad*16
            int co = (kt * 64 + quad * 16) ^ ((l16 & 7) << 4);
            a0v = *reinterpret_cast<const v8s*>(Asb + l16 * 256 + co);
            a1v = *reinterpret_cast<const v8s*>(Asb + (16 + l16) * 256 + co);
        } else {
            // A from global root rows (contiguous, coalesced)
            int ak = (kt - 4) * 32 + quad * 8;
            a0v = *reinterpret_cast<const v8s*>(hin + (size_t)(base + l16) * DCH + ak);
            a1v = *reinterpret_cast<const v8s*>(hin + (size_t)(base + 16 + l16) * DCH + ak);
        }
        #pragma unroll
        for (int nt = 0; nt < 8; nt++) {
            v8s b = *reinterpret_cast<const v8s*>(frag + (((size_t)(kt * 8 + nt)) * 64 + lane) * 8);
            acc[0][nt] = __builtin_amdgcn_mfma_f32_16x16x32_bf16(a0v, b, acc[0][nt], 0, 0, 0);
            acc[1][nt] = __builtin_amdgcn_mfma_f32_16x16x32_bf16(a1v, b, acc[1][nt], 0, 0, 0);
        }
    }
    #pragma unroll
    for (int h = 0; h < 2; h++) {
        int mbase = base + h * 16 + quad * 4;
        #pragma unroll
        for (int nt = 0; nt < 8; nt++) {
            int n = nt * 16 + l16;
            float bv = bias[n];
            #pragma unroll
            for (int r = 0; r < 4; r++) {
                float v = acc[h][nt][r] + bv;
                if (relu) v = fmaxf(v, 0.f);
                hout[(size_t)(mbase + r) * DCH + n] = f2bf(v);
            }
        }
    }
}

// ---------------- pooling stage 1: segmented sum into psum (batch sorted) ----------------
__global__ void __launch_bounds__(128) pool_kernel(const unsigned short* __restrict__ h,
                                                   const int* __restrict__ batch,
                                                   float* __restrict__ psum) {
    int c  = threadIdx.x; // 0..127
    int n0 = blockIdx.x * PCH;
    int n1 = n0 + PCH < N_NODES ? n0 + PCH : N_NODES;
    if (n0 >= n1) return;
    int cur = clampi(batch[n0], 0, N_GRAPHS - 1);
    float acc = 0.f;
    for (int n = n0; n < n1; n++) {
        int g = clampi(batch[n], 0, N_GRAPHS - 1);
        if (g != cur) {
            atomicAdd(&psum[cur * DCH + c], acc);
            acc = 0.f; cur = g;
        }
        acc += bf2f(h[(size_t)n * DCH + c]);
    }
    atomicAdd(&psum[cur * DCH + c], acc);
}

// ---------------- pooling stage 2: out[g] = (psum[g]/cnt_g) @ Wl + bl ----------------
static __device__ __forceinline__ int lowerb(const int* __restrict__ a, int n, int key) {
    int lo = 0, hi = n;
    while (lo < hi) { int mid = (lo + hi) >> 1; if (a[mid] < key) lo = mid + 1; else hi = mid; }
    return lo;
}

__global__ void __launch_bounds__(64) final_kernel(const float* __restrict__ psum,
                                                   const int* __restrict__ batch,
                                                   const float* __restrict__ Wl, const float* __restrict__ bl,
                                                   float* __restrict__ out) {
    __shared__ float ps[DCH];
    __shared__ int bounds[2];
    int g = blockIdx.x, tid = threadIdx.x;
    if (tid == 0) {
        bounds[0] = lowerb(batch, N_NODES, g);
        bounds[1] = lowerb(batch, N_NODES, g + 1);
    }
    __syncthreads();
    int cnt = bounds[1] - bounds[0];
    float inv = 1.0f / (float)(cnt > 1 ? cnt : 1);
    ps[tid] = psum[g * DCH + tid] * inv;
    ps[tid + 64] = psum[g * DCH + tid + 64] * inv;
    __syncthreads();
    float o = 0.f;
    #pragma unroll 4
    for (int c = 0; c < DCH; c++) o += ps[c] * Wl[c * DOUT + tid];
    out[g * DOUT + tid] = o + bl[tid];
}

extern "C" void kernel_launch(void* const* d_in, const int* in_sizes, int n_in,
                              void* d_out, int out_size, void* d_ws, size_t ws_size,
                              hipStream_t stream) {
    const float* x     = (const float*)d_in[0];
    const int*   edge  = (const int*)d_in[1];
    const int*   src   = edge;
    const int*   dst   = edge + N_EDGES;
    const int*   batch = (const int*)d_in[2];
    const float* W1rel  = (const float*)d_in[3];
    const float* b1     = (const float*)d_in[4];
    const float* W1root = (const float*)d_in[5];
    const float* W2rel  = (const float*)d_in[6];
    const float* b2     = (const float*)d_in[7];
    const float* W2root = (const float*)d_in[8];
    const float* W3rel  = (const float*)d_in[9];
    const float* b3     = (const float*)d_in[10];
    const float* W3root = (const float*)d_in[11];
    const float* Wl     = (const float*)d_in[12];
    const float* bl     = (const float*)d_in[13];
    float* out = (float*)d_out;

    char* ws = (char*)d_ws;
    size_t off = 0;
    auto carve = [&](size_t bytes) -> void* {
        void* p = ws + off;
        off += (bytes + 255) & ~(size_t)255;
        return p;
    };
    // ~58.3 MiB total; bucket region reuses B1 (free during CSR build)
    int*            rowptr  = (int*)carve((size_t)(N_NODES + 1) * 4);
    int*            csr     = (int*)carve((size_t)(N_EDGES + 64) * 4);   // +64: stream prefetch slack
    int*            gcur    = (int*)carve((size_t)PADB * 4 + (size_t)N_GRAPHS * DCH * 4); // gcur + psum, one memset
    float*          psum    = (float*)(gcur + PADB);
    int*            hoffG   = (int*)carve((size_t)PADB * 4);
    unsigned short* frag    = (unsigned short*)carve((size_t)3 * 8 * 8 * 64 * 8 * 2);
    unsigned short* B1      = (unsigned short*)carve((size_t)(N_NODES + 1) * DCH * 2);   // +1 zero row
    unsigned short* B2      = (unsigned short*)carve((size_t)(N_NODES + 1) * DCH * 2);   // +1 zero row
    uint2*          region  = (uint2*)B1;   // 391*4608*8 = 14.4 MB <= 25.6 MB (zero row is beyond region)

    hipMemsetAsync(gcur, 0, (size_t)PADB * 4 + (size_t)N_GRAPHS * DCH * 4, stream);
    // zero rows (gather target for padded lanes); never overwritten by any kernel
    hipMemsetAsync(B1 + (size_t)N_NODES * DCH, 0, (size_t)DCH * 2, stream);
    hipMemsetAsync(B2 + (size_t)N_NODES * DCH, 0, (size_t)DCH * 2, stream);

    // CSR build: binA -> scan -> binFinish
    binA_kernel<<<(N_EDGES + CHUNK - 1) / CHUNK, 256, 0, stream>>>(src, dst, gcur, region);
    scan_kernel<<<1, 256, 0, stream>>>(gcur, hoffG, rowptr);
    binFinish_kernel<<<NB, 256, 0, stream>>>(region, gcur, hoffG, rowptr, csr);
    // features + weights
    cvt_kernel<<<(N_NODES * DCH / 4 + 255) / 256, 256, 0, stream>>>(x, B2);
    wfrag_kernel<<<(3 * 8 * 8 * 64 + 255) / 256, 256, 0, stream>>>(W1rel, W1root, W2rel, W2root, W3rel, W3root, frag);

    const int layerGrid = (N_NODES + 63) / 64;   // 1563

    // fused layers (agg + gemm + bias + relu); ping-pong B2 -> B1 -> B2 -> B1
    layer_kernel<<<layerGrid, 128, 0, stream>>>(B2, rowptr, csr, frag,         b1, B1, 1);
    layer_kernel<<<layerGrid, 128, 0, stream>>>(B1, rowptr, csr, frag + 32768, b2, B2, 1);
    layer_kernel<<<layerGrid, 128, 0, stream>>>(B2, rowptr, csr, frag + 65536, b3, B1, 0);

    // pooling: wide segmented sum, then per-graph matvec
    pool_kernel<<<(N_NODES + PCH - 1) / PCH, 128, 0, stream>>>(B1, batch, psum);
    final_kernel<<<N_GRAPHS, 64, 0, stream>>>(psum, batch, Wl, bl, out);
}

// Round 3
// 411.444 us; speedup vs baseline: 1.0867x; 1.0083x over previous
//
#include <hip/hip_runtime.h>
#include <hip/hip_bf16.h>

#define N_NODES  100000
#define N_EDGES  1600000
#define N_GRAPHS 256
#define DCH      128
#define DOUT     64
#define NB       391      // buckets = ceil(100000/256)
#define PADB     512
#define SLACK    4608     // per-bucket region capacity (mean 4096 + 8 sigma)
#define CHUNK    2048     // edges per binA block

typedef short v8s __attribute__((ext_vector_type(8)));
typedef float v4f __attribute__((ext_vector_type(4)));

static __device__ __forceinline__ float bf2f(unsigned short u) {
    unsigned int x = ((unsigned int)u) << 16;
    return __builtin_bit_cast(float, x);
}
static __device__ __forceinline__ unsigned short f2bf(float f) {
    unsigned int x = __builtin_bit_cast(unsigned int, f);
    unsigned int r = (x + 0x7fffu + ((x >> 16) & 1u)) >> 16;
    return (unsigned short)r;
}
static __device__ __forceinline__ int clampi(int v, int lo, int hi) {
    return v < lo ? lo : (v > hi ? hi : v);
}

// ---------------- edge binning pass A: partition edges into dst>>8 buckets ----------------
__global__ void __launch_bounds__(256) binA_kernel(const int* __restrict__ src, const int* __restrict__ dst,
                                                   int* __restrict__ gcur, uint2* __restrict__ region) {
    __shared__ uint2 stage[CHUNK];          // 16 KB
    __shared__ int hcnt[PADB], hcnt2[PADB], hoff[PADB], garr[PADB];
    __shared__ int s2[256];
    int tid = threadIdx.x;
    int e0  = blockIdx.x * CHUNK;
    int nedge = N_EDGES - e0; if (nedge > CHUNK) nedge = CHUNK;

    for (int b = tid; b < PADB; b += 256) { hcnt[b] = 0; hcnt2[b] = 0; }
    __syncthreads();

    int es[CHUNK / 256], ed[CHUNK / 256];
    #pragma unroll
    for (int j = 0; j < CHUNK / 256; j++) {
        int e = e0 + j * 256 + tid;
        if (e < N_EDGES) {
            es[j] = clampi(src[e], 0, N_NODES - 1);
            ed[j] = clampi(dst[e], 0, N_NODES - 1);
            atomicAdd(&hcnt[ed[j] >> 8], 1);
        } else { es[j] = -1; ed[j] = 0; }
    }
    __syncthreads();

    int v0 = hcnt[2 * tid], v1 = hcnt[2 * tid + 1];
    s2[tid] = v0 + v1; __syncthreads();
    for (int off = 1; off < 256; off <<= 1) {
        int x = (tid >= off) ? s2[tid - off] : 0;
        __syncthreads();
        s2[tid] += x;
        __syncthreads();
    }
    int excl = s2[tid] - (v0 + v1);
    hoff[2 * tid] = excl; hoff[2 * tid + 1] = excl + v0;
    __syncthreads();

    for (int b = tid; b < NB; b += 256) {
        int c = hcnt[b];
        garr[b] = b * SLACK + ((c > 0) ? atomicAdd(&gcur[b], c) : 0);
    }
    __syncthreads();

    #pragma unroll
    for (int j = 0; j < CHUNK / 256; j++) {
        if (es[j] >= 0) {
            int b = ed[j] >> 8;
            int pos = atomicAdd(&hcnt2[b], 1) + hoff[b];
            stage[pos] = (uint2){(unsigned)es[j], (unsigned)ed[j]};
        }
    }
    __syncthreads();

    for (int i = tid; i < nedge; i += 256) {
        uint2 en = stage[i];
        int b = (int)(en.y >> 8);
        int gpos = garr[b] + (i - hoff[b]);
        if (gpos < (b + 1) * SLACK) region[gpos] = en;
    }
}

// ---------------- scan: global bucket prefix ----------------
__global__ void __launch_bounds__(256) scan_kernel(const int* __restrict__ gcur,
                                                   int* __restrict__ hoffG, int* __restrict__ rowptr) {
    __shared__ int s2[256];
    int tid = threadIdx.x;
    int c0 = gcur[2 * tid];     if (c0 > SLACK) c0 = SLACK;
    int c1 = gcur[2 * tid + 1]; if (c1 > SLACK) c1 = SLACK;
    s2[tid] = c0 + c1; __syncthreads();
    for (int off = 1; off < 256; off <<= 1) {
        int x = (tid >= off) ? s2[tid - off] : 0;
        __syncthreads();
        s2[tid] += x;
        __syncthreads();
    }
    int excl = s2[tid] - (c0 + c1);
    hoffG[2 * tid] = excl; hoffG[2 * tid + 1] = excl + c0;
    if (tid == 255) rowptr[N_NODES] = s2[255];
}

// ---------------- binFinish: per-bucket degree + rowptr + csr scatter ----------------
__global__ void __launch_bounds__(256) binFinish_kernel(const uint2* __restrict__ region, const int* __restrict__ gcur,
                                                        const int* __restrict__ hoffG,
                                                        int* __restrict__ rowptr, int* __restrict__ csr) {
    __shared__ int h[256], sc[256], cur[256];
    int b = blockIdx.x, tid = threadIdx.x;
    h[tid] = 0;
    int base = hoffG[b];
    int size = gcur[b]; if (size > SLACK) size = SLACK;
    int node0 = b * 256;
    __syncthreads();
    for (int j = tid; j < size; j += 256) {
        unsigned loc = region[b * SLACK + j].y - (unsigned)node0;
        if (loc < 256u) atomicAdd(&h[loc], 1);
    }
    __syncthreads();
    int v = h[tid]; sc[tid] = v; __syncthreads();
    for (int off = 1; off < 256; off <<= 1) {
        int x = (tid >= off) ? sc[tid - off] : 0;
        __syncthreads();
        sc[tid] += x;
        __syncthreads();
    }
    int myptr = base + sc[tid] - v;
    int node = node0 + tid;
    if (node < N_NODES) rowptr[node] = myptr;
    cur[tid] = myptr;
    __syncthreads();
    for (int j = tid; j < size; j += 256) {
        uint2 en = region[b * SLACK + j];
        unsigned loc = en.y - (unsigned)node0;
        if (loc < 256u) {
            int p = atomicAdd(&cur[loc], 1);
            if (p >= 0 && p < N_EDGES) csr[p] = (int)en.x;
        }
    }
}

// ---------------- fused prep: cvt (fp32->bf16) + weight fragments + zero rows ----------------
__global__ void __launch_bounds__(256) prep_kernel(const float* __restrict__ x, unsigned short* __restrict__ B2,
                                                   const float* __restrict__ W1rel, const float* __restrict__ W1root,
                                                   const float* __restrict__ W2rel, const float* __restrict__ W2root,
                                                   const float* __restrict__ W3rel, const float* __restrict__ W3root,
                                                   unsigned short* __restrict__ frag,
                                                   unsigned short* __restrict__ z1, unsigned short* __restrict__ z2) {
    int bid = blockIdx.x, tid = threadIdx.x;
    if (bid < 12500) {                       // cvt: 12500*256*4 == N_NODES*DCH exactly
        size_t i = ((size_t)bid * 256 + tid) * 4;
        float4 f = *reinterpret_cast<const float4*>(x + i);
        uint2 o;
        o.x = ((unsigned)f2bf(f.y) << 16) | (unsigned)f2bf(f.x);
        o.y = ((unsigned)f2bf(f.w) << 16) | (unsigned)f2bf(f.z);
        *reinterpret_cast<uint2*>(B2 + i) = o;
    } else if (bid < 12548) {                // wfrag: 48*256 == 12288 == 3*8*8*64
        int gid = (bid - 12500) * 256 + tid;
        int lane = gid & 63;
        int nt   = (gid >> 6) & 7;
        int kt   = (gid >> 9) & 7;
        int L    = gid >> 12;
        const float* rel  = (L == 0) ? W1rel  : (L == 1) ? W2rel  : W3rel;
        const float* root = (L == 0) ? W1root : (L == 1) ? W2root : W3root;
        int n  = nt * 16 + (lane & 15);
        int k0 = kt * 32 + (lane >> 4) * 8;
        unsigned short o[8];
        #pragma unroll
        for (int j = 0; j < 8; j++) {
            int k = k0 + j;
            float w = (k < 128) ? rel[k * 128 + n] : root[(k - 128) * 128 + n];
            o[j] = f2bf(w);
        }
        uint4 u;
        u.x = (unsigned)o[0] | ((unsigned)o[1] << 16);
        u.y = (unsigned)o[2] | ((unsigned)o[3] << 16);
        u.z = (unsigned)o[4] | ((unsigned)o[5] << 16);
        u.w = (unsigned)o[6] | ((unsigned)o[7] << 16);
        *reinterpret_cast<uint4*>(frag + (size_t)gid * 8) = u;
    } else {                                 // zero rows (gather target for padded lanes)
        if (tid < 64)       reinterpret_cast<unsigned*>(z1)[tid] = 0;
        else if (tid < 128) reinterpret_cast<unsigned*>(z2)[tid - 64] = 0;
    }
}

// ---------------- fused layer: agg (mean gather) + GEMM + bias + relu/pool ----------------
// 256-thread blocks, 4 waves; each wave owns 16 output rows + a private 4 KB LDS slab
// (no barriers anywhere). Total waves = 100000/16 = 6250 -> 24.4 waves/CU ceiling
// (vs 12.2 at 32 rows/wave: the round-2 occupancy cap was the grid, not the block).
// Agg = flat edge stream in 16-edge chunks: prefetch next csr chunk, batch-issue 16
// saddr gathers (readlane -> SGPR row index, one vmcnt window), scalar-pipe node
// boundary cascade; padded lanes gather the all-zero row N_NODES.
// mode: 0 = plain store, 1 = relu store, 2 = pooled (atomicAdd per-graph sums into
// psum, nothing stored to hout -> saves 51 MB round-trip + the pool dispatch).
__global__ void __launch_bounds__(256, 6) layer_kernel(
    const unsigned short* __restrict__ hin,   // N_NODES+1 rows; row N_NODES is zero
    const int* __restrict__ rowptr, const int* __restrict__ csr,
    const unsigned short* __restrict__ frag, const float* __restrict__ bias,
    unsigned short* __restrict__ hout,
    const int* __restrict__ batch, float* __restrict__ psum, int mode)
{
    __shared__ __attribute__((aligned(16))) unsigned short As[4][16 * DCH];  // 16 KB
    const int wave = threadIdx.x >> 6;
    const int lane = threadIdx.x & 63;
    const int l16  = lane & 15;
    const int quad = lane >> 4;
    const int base = blockIdx.x * 64 + wave * 16;
    if (base >= N_NODES) return;             // no barriers in kernel: early-out safe

    char* Asb = reinterpret_cast<char*>(As[wave]);

    // rowptr[base .. base+16]: one coalesced load; readlane thereafter (SGPR)
    int ridx = base + (lane < 17 ? lane : 16);
    if (ridx > N_NODES) ridx = N_NODES;
    int rp = rowptr[ridx];
    const int R0 = __builtin_amdgcn_readlane(rp, 0);
    const int R1 = __builtin_amdgcn_readlane(rp, 16);

    int ni     = 0;                          // current node (0..15), scalar
    int nstart = R0;
    int nend   = __builtin_amdgcn_readlane(rp, 1);
    float a0 = 0.f, a1 = 0.f;

    int t0  = csr[R0 + l16];                 // csr over-allocated +64
    int idx = (R0 + l16 < R1) ? t0 : N_NODES;

    for (int e0 = R0; e0 < R1; e0 += 16) {
        int en   = e0 + 16 + l16;            // prefetch next csr chunk
        int tn   = csr[en];
        int idxn = (en < R1) ? tn : N_NODES;

        unsigned v[16];                      // 16 independent gathers, one vmcnt window
        #pragma unroll
        for (int j = 0; j < 16; j++) {
            int s = __builtin_amdgcn_readlane(idx, j);
            v[j] = *reinterpret_cast<const unsigned*>(hin + (size_t)s * DCH + lane * 2);
        }

        #pragma unroll
        for (int j = 0; j < 16; j++) {
            int e = e0 + j;                  // uniform
            while (ni < 16 && e == nend) {   // finalize node ni (scalar-pipe cascade)
                int deg = nend - nstart;
                float inv = 1.0f / (float)(deg > 1 ? deg : 1);
                unsigned o = ((unsigned)f2bf(a1 * inv) << 16) | (unsigned)f2bf(a0 * inv);
                *reinterpret_cast<unsigned*>(Asb + ni * 256 + ((lane * 4) ^ ((ni & 7) << 4))) = o;
                a0 = 0.f; a1 = 0.f;
                ni++;
                nstart = nend;
                nend = __builtin_amdgcn_readlane(rp, ni + 1 < 17 ? ni + 1 : 16);
            }
            a0 += bf2f((unsigned short)(v[j] & 0xffffu));
            a1 += bf2f((unsigned short)(v[j] >> 16));
        }
        idx = idxn;
    }
    while (ni < 16) {                        // finalize tail
        int deg = nend - nstart;
        float inv = 1.0f / (float)(deg > 1 ? deg : 1);
        unsigned o = ((unsigned)f2bf(a1 * inv) << 16) | (unsigned)f2bf(a0 * inv);
        *reinterpret_cast<unsigned*>(Asb + ni * 256 + ((lane * 4) ^ ((ni & 7) << 4))) = o;
        a0 = 0.f; a1 = 0.f;
        ni++;
        nstart = nend;
        nend = __builtin_amdgcn_readlane(rp, ni + 1 < 17 ? ni + 1 : 16);
    }
    // wave-private LDS: compiler lgkmcnt covers write->read dep; no barrier.

    // ---------- MFMA: M=16 tile, [agg | root] @ [Wrel; Wroot] ----------
    v4f acc[8];
    #pragma unroll
    for (int nt = 0; nt < 8; nt++) acc[nt] = (v4f){0.f, 0.f, 0.f, 0.f};

    #pragma unroll
    for (int kt = 0; kt < 8; kt++) {
        v8s av;
        if (kt < 4) {
            int co = (kt * 64 + quad * 16) ^ ((l16 & 7) << 4);
            av = *reinterpret_cast<const v8s*>(Asb + l16 * 256 + co);
        } else {
            int ak = (kt - 4) * 32 + quad * 8;
            int row = base + l16; if (row > N_NODES) row = N_NODES;
            av = *reinterpret_cast<const v8s*>(hin + (size_t)row * DCH + ak);
        }
        #pragma unroll
        for (int nt = 0; nt < 8; nt++) {
            v8s b = *reinterpret_cast<const v8s*>(frag + (((size_t)(kt * 8 + nt)) * 64 + lane) * 8);
            acc[nt] = __builtin_amdgcn_mfma_f32_16x16x32_bf16(av, b, acc[nt], 0, 0, 0);
        }
    }

    if (mode != 2) {
        #pragma unroll
        for (int nt = 0; nt < 8; nt++) {
            int n = nt * 16 + l16;
            float bv = bias[n];
            #pragma unroll
            for (int r = 0; r < 4; r++) {
                int row = base + quad * 4 + r;
                if (row < N_NODES) {
                    float v = acc[nt][r] + bv;
                    if (mode == 1) v = fmaxf(v, 0.f);
                    hout[(size_t)row * DCH + n] = f2bf(v);
                }
            }
        }
    } else {
        // pooled epilogue: per-graph sums (mean + matvec applied in final_kernel)
        int last = base + 15;
        bool fast = (last < N_NODES) && (batch[base] == batch[last]);
        if (fast) {
            int g = batch[base];             // all 16 rows same graph (~94% of waves)
            #pragma unroll
            for (int nt = 0; nt < 8; nt++) {
                int n = nt * 16 + l16;
                float s = acc[nt][0] + acc[nt][1] + acc[nt][2] + acc[nt][3] + 4.0f * bias[n];
                s += __shfl_xor(s, 16);      // reduce across quads (rows)
                s += __shfl_xor(s, 32);
                if (quad == 0) atomicAdd(&psum[g * DCH + n], s);
            }
        } else {
            int g[4];
            #pragma unroll
            for (int r = 0; r < 4; r++) {
                int row = base + quad * 4 + r;
                g[r] = (row < N_NODES) ? batch[row] : -1;
            }
            #pragma unroll
            for (int nt = 0; nt < 8; nt++) {
                int n = nt * 16 + l16;
                float bv = bias[n];
                float s = 0.f; int cg = -1;
                #pragma unroll
                for (int r = 0; r < 4; r++) {
                    if (g[r] < 0) continue;
                    if (g[r] != cg) {
                        if (cg >= 0) atomicAdd(&psum[cg * DCH + n], s);
                        s = 0.f; cg = g[r];
                    }
                    s += acc[nt][r] + bv;
                }
                if (cg >= 0) atomicAdd(&psum[cg * DCH + n], s);
            }
        }
    }
}

// ---------------- final: out[g] = (psum[g]/cnt_g) @ Wl + bl ----------------
static __device__ __forceinline__ int lowerb(const int* __restrict__ a, int n, int key) {
    int lo = 0, hi = n;
    while (lo < hi) { int mid = (lo + hi) >> 1; if (a[mid] < key) lo = mid + 1; else hi = mid; }
    return lo;
}

__global__ void __launch_bounds__(64) final_kernel(const float* __restrict__ psum,
                                                   const int* __restrict__ batch,
                                                   const float* __restrict__ Wl, const float* __restrict__ bl,
                                                   float* __restrict__ out) {
    __shared__ float ps[DCH];
    __shared__ int bounds[2];
    int g = blockIdx.x, tid = threadIdx.x;
    if (tid == 0) {
        bounds[0] = lowerb(batch, N_NODES, g);
        bounds[1] = lowerb(batch, N_NODES, g + 1);
    }
    __syncthreads();
    int cnt = bounds[1] - bounds[0];
    float inv = 1.0f / (float)(cnt > 1 ? cnt : 1);
    ps[tid] = psum[g * DCH + tid] * inv;
    ps[tid + 64] = psum[g * DCH + tid + 64] * inv;
    __syncthreads();
    float o = 0.f;
    #pragma unroll 4
    for (int c = 0; c < DCH; c++) o += ps[c] * Wl[c * DOUT + tid];
    out[g * DOUT + tid] = o + bl[tid];
}

extern "C" void kernel_launch(void* const* d_in, const int* in_sizes, int n_in,
                              void* d_out, int out_size, void* d_ws, size_t ws_size,
                              hipStream_t stream) {
    const float* x     = (const float*)d_in[0];
    const int*   edge  = (const int*)d_in[1];
    const int*   src   = edge;
    const int*   dst   = edge + N_EDGES;
    const int*   batch = (const int*)d_in[2];
    const float* W1rel  = (const float*)d_in[3];
    const float* b1     = (const float*)d_in[4];
    const float* W1root = (const float*)d_in[5];
    const float* W2rel  = (const float*)d_in[6];
    const float* b2     = (const float*)d_in[7];
    const float* W2root = (const float*)d_in[8];
    const float* W3rel  = (const float*)d_in[9];
    const float* b3     = (const float*)d_in[10];
    const float* W3root = (const float*)d_in[11];
    const float* Wl     = (const float*)d_in[12];
    const float* bl     = (const float*)d_in[13];
    float* out = (float*)d_out;

    char* ws = (char*)d_ws;
    size_t off = 0;
    auto carve = [&](size_t bytes) -> void* {
        void* p = ws + off;
        off += (bytes + 255) & ~(size_t)255;
        return p;
    };
    int*            rowptr  = (int*)carve((size_t)(N_NODES + 1) * 4);
    int*            csr     = (int*)carve((size_t)(N_EDGES + 64) * 4);   // +64: stream prefetch slack
    int*            gcur    = (int*)carve((size_t)PADB * 4 + (size_t)N_GRAPHS * DCH * 4); // gcur + psum, one memset
    float*          psum    = (float*)(gcur + PADB);
    int*            hoffG   = (int*)carve((size_t)PADB * 4);
    unsigned short* frag    = (unsigned short*)carve((size_t)3 * 8 * 8 * 64 * 8 * 2);
    unsigned short* B1      = (unsigned short*)carve((size_t)(N_NODES + 1) * DCH * 2);   // +1 zero row
    unsigned short* B2      = (unsigned short*)carve((size_t)(N_NODES + 1) * DCH * 2);   // +1 zero row
    uint2*          region  = (uint2*)B1;   // 391*4608*8 = 14.4 MB <= 25.6 MB

    hipMemsetAsync(gcur, 0, (size_t)PADB * 4 + (size_t)N_GRAPHS * DCH * 4, stream);

    // CSR build: binA -> scan -> binFinish
    binA_kernel<<<(N_EDGES + CHUNK - 1) / CHUNK, 256, 0, stream>>>(src, dst, gcur, region);
    scan_kernel<<<1, 256, 0, stream>>>(gcur, hoffG, rowptr);
    binFinish_kernel<<<NB, 256, 0, stream>>>(region, gcur, hoffG, rowptr, csr);
    // features + weights + zero rows, one dispatch
    prep_kernel<<<12549, 256, 0, stream>>>(x, B2, W1rel, W1root, W2rel, W2root, W3rel, W3root,
                                           frag, B1 + (size_t)N_NODES * DCH, B2 + (size_t)N_NODES * DCH);

    const int layerGrid = (N_NODES + 63) / 64;   // 1563 blocks x 4 waves x 16 rows

    // fused layers; ping-pong B2 -> B1 -> B2; layer 3 pools directly into psum
    layer_kernel<<<layerGrid, 256, 0, stream>>>(B2, rowptr, csr, frag,         b1, B1, batch, psum, 1);
    layer_kernel<<<layerGrid, 256, 0, stream>>>(B1, rowptr, csr, frag + 32768, b2, B2, batch, psum, 1);
    layer_kernel<<<layerGrid, 256, 0, stream>>>(B2, rowptr, csr, frag + 65536, b3, B1, batch, psum, 2);

    final_kernel<<<N_GRAPHS, 64, 0, stream>>>(psum, batch, Wl, bl, out);
}

// Round 4
// 410.951 us; speedup vs baseline: 1.0880x; 1.0012x over previous
//
#include <hip/hip_runtime.h>
#include <hip/hip_bf16.h>

#define N_NODES  100000
#define N_EDGES  1600000
#define N_GRAPHS 256
#define DCH      128
#define DOUT     64
#define NB       391      // buckets = ceil(100000/256)
#define PADB     512
#define SLACK    4608     // per-bucket region capacity (mean 4096 + 8 sigma)
#define CHUNK    2048     // edges per binA block

typedef short v8s __attribute__((ext_vector_type(8)));
typedef float v4f __attribute__((ext_vector_type(4)));

static __device__ __forceinline__ float bf2f(unsigned short u) {
    unsigned int x = ((unsigned int)u) << 16;
    return __builtin_bit_cast(float, x);
}
static __device__ __forceinline__ unsigned short f2bf(float f) {
    unsigned int x = __builtin_bit_cast(unsigned int, f);
    unsigned int r = (x + 0x7fffu + ((x >> 16) & 1u)) >> 16;
    return (unsigned short)r;
}
static __device__ __forceinline__ int clampi(int v, int lo, int hi) {
    return v < lo ? lo : (v > hi ? hi : v);
}

// ---------------- edge binning pass A: partition edges into dst>>8 buckets ----------------
__global__ void __launch_bounds__(256) binA_kernel(const int* __restrict__ src, const int* __restrict__ dst,
                                                   int* __restrict__ gcur, uint2* __restrict__ region) {
    __shared__ uint2 stage[CHUNK];          // 16 KB
    __shared__ int hcnt[PADB], hcnt2[PADB], hoff[PADB], garr[PADB];
    __shared__ int s2[256];
    int tid = threadIdx.x;
    int e0  = blockIdx.x * CHUNK;
    int nedge = N_EDGES - e0; if (nedge > CHUNK) nedge = CHUNK;

    for (int b = tid; b < PADB; b += 256) { hcnt[b] = 0; hcnt2[b] = 0; }
    __syncthreads();

    int es[CHUNK / 256], ed[CHUNK / 256];
    #pragma unroll
    for (int j = 0; j < CHUNK / 256; j++) {
        int e = e0 + j * 256 + tid;
        if (e < N_EDGES) {
            es[j] = clampi(src[e], 0, N_NODES - 1);
            ed[j] = clampi(dst[e], 0, N_NODES - 1);
            atomicAdd(&hcnt[ed[j] >> 8], 1);
        } else { es[j] = -1; ed[j] = 0; }
    }
    __syncthreads();

    int v0 = hcnt[2 * tid], v1 = hcnt[2 * tid + 1];
    s2[tid] = v0 + v1; __syncthreads();
    for (int off = 1; off < 256; off <<= 1) {
        int x = (tid >= off) ? s2[tid - off] : 0;
        __syncthreads();
        s2[tid] += x;
        __syncthreads();
    }
    int excl = s2[tid] - (v0 + v1);
    hoff[2 * tid] = excl; hoff[2 * tid + 1] = excl + v0;
    __syncthreads();

    for (int b = tid; b < NB; b += 256) {
        int c = hcnt[b];
        garr[b] = b * SLACK + ((c > 0) ? atomicAdd(&gcur[b], c) : 0);
    }
    __syncthreads();

    #pragma unroll
    for (int j = 0; j < CHUNK / 256; j++) {
        if (es[j] >= 0) {
            int b = ed[j] >> 8;
            int pos = atomicAdd(&hcnt2[b], 1) + hoff[b];
            stage[pos] = (uint2){(unsigned)es[j], (unsigned)ed[j]};
        }
    }
    __syncthreads();

    for (int i = tid; i < nedge; i += 256) {
        uint2 en = stage[i];
        int b = (int)(en.y >> 8);
        int gpos = garr[b] + (i - hoff[b]);
        if (gpos < (b + 1) * SLACK) region[gpos] = en;
    }
}

// ---------------- scan: global bucket prefix ----------------
__global__ void __launch_bounds__(256) scan_kernel(const int* __restrict__ gcur,
                                                   int* __restrict__ hoffG, int* __restrict__ rowptr) {
    __shared__ int s2[256];
    int tid = threadIdx.x;
    int c0 = gcur[2 * tid];     if (c0 > SLACK) c0 = SLACK;
    int c1 = gcur[2 * tid + 1]; if (c1 > SLACK) c1 = SLACK;
    s2[tid] = c0 + c1; __syncthreads();
    for (int off = 1; off < 256; off <<= 1) {
        int x = (tid >= off) ? s2[tid - off] : 0;
        __syncthreads();
        s2[tid] += x;
        __syncthreads();
    }
    int excl = s2[tid] - (c0 + c1);
    hoffG[2 * tid] = excl; hoffG[2 * tid + 1] = excl + c0;
    if (tid == 255) rowptr[N_NODES] = s2[255];
}

// ---------------- binFinish: per-bucket degree + rowptr + csr scatter ----------------
__global__ void __launch_bounds__(256) binFinish_kernel(const uint2* __restrict__ region, const int* __restrict__ gcur,
                                                        const int* __restrict__ hoffG,
                                                        int* __restrict__ rowptr, int* __restrict__ csr) {
    __shared__ int h[256], sc[256], cur[256];
    int b = blockIdx.x, tid = threadIdx.x;
    h[tid] = 0;
    int base = hoffG[b];
    int size = gcur[b]; if (size > SLACK) size = SLACK;
    int node0 = b * 256;
    __syncthreads();
    for (int j = tid; j < size; j += 256) {
        unsigned loc = region[b * SLACK + j].y - (unsigned)node0;
        if (loc < 256u) atomicAdd(&h[loc], 1);
    }
    __syncthreads();
    int v = h[tid]; sc[tid] = v; __syncthreads();
    for (int off = 1; off < 256; off <<= 1) {
        int x = (tid >= off) ? sc[tid - off] : 0;
        __syncthreads();
        sc[tid] += x;
        __syncthreads();
    }
    int myptr = base + sc[tid] - v;
    int node = node0 + tid;
    if (node < N_NODES) rowptr[node] = myptr;
    cur[tid] = myptr;
    __syncthreads();
    for (int j = tid; j < size; j += 256) {
        uint2 en = region[b * SLACK + j];
        unsigned loc = en.y - (unsigned)node0;
        if (loc < 256u) {
            int p = atomicAdd(&cur[loc], 1);
            if (p >= 0 && p < N_EDGES) csr[p] = (int)en.x;
        }
    }
}

// ---------------- fused prep: cvt + weight fragments + zero rows + gcur/psum clear ----------------
__global__ void __launch_bounds__(256) prep_kernel(const float* __restrict__ x, unsigned short* __restrict__ B2,
                                                   const float* __restrict__ W1rel, const float* __restrict__ W1root,
                                                   const float* __restrict__ W2rel, const float* __restrict__ W2root,
                                                   const float* __restrict__ W3rel, const float* __restrict__ W3root,
                                                   unsigned short* __restrict__ frag,
                                                   unsigned short* __restrict__ z1, unsigned short* __restrict__ z2,
                                                   int* __restrict__ gcur, float* __restrict__ psum) {
    int bid = blockIdx.x, tid = threadIdx.x;
    if (bid < 12500) {                       // cvt: 12500*256*4 == N_NODES*DCH exactly
        size_t i = ((size_t)bid * 256 + tid) * 4;
        float4 f = *reinterpret_cast<const float4*>(x + i);
        uint2 o;
        o.x = ((unsigned)f2bf(f.y) << 16) | (unsigned)f2bf(f.x);
        o.y = ((unsigned)f2bf(f.w) << 16) | (unsigned)f2bf(f.z);
        *reinterpret_cast<uint2*>(B2 + i) = o;
    } else if (bid < 12548) {                // wfrag: 48*256 == 12288 == 3*8*8*64
        int gid = (bid - 12500) * 256 + tid;
        int lane = gid & 63;
        int nt   = (gid >> 6) & 7;
        int kt   = (gid >> 9) & 7;
        int L    = gid >> 12;
        const float* rel  = (L == 0) ? W1rel  : (L == 1) ? W2rel  : W3rel;
        const float* root = (L == 0) ? W1root : (L == 1) ? W2root : W3root;
        int n  = nt * 16 + (lane & 15);
        int k0 = kt * 32 + (lane >> 4) * 8;
        unsigned short o[8];
        #pragma unroll
        for (int j = 0; j < 8; j++) {
            int k = k0 + j;
            float w = (k < 128) ? rel[k * 128 + n] : root[(k - 128) * 128 + n];
            o[j] = f2bf(w);
        }
        uint4 u;
        u.x = (unsigned)o[0] | ((unsigned)o[1] << 16);
        u.y = (unsigned)o[2] | ((unsigned)o[3] << 16);
        u.z = (unsigned)o[4] | ((unsigned)o[5] << 16);
        u.w = (unsigned)o[6] | ((unsigned)o[7] << 16);
        *reinterpret_cast<uint4*>(frag + (size_t)gid * 8) = u;
    } else if (bid == 12548) {               // zero rows + gcur clear
        if (tid < 64)       reinterpret_cast<unsigned*>(z1)[tid] = 0;
        else if (tid < 128) reinterpret_cast<unsigned*>(z2)[tid - 64] = 0;
        gcur[tid] = 0; gcur[tid + 256] = 0;
    } else {                                 // psum clear: 32 blocks * 256 * float4 = 32768 floats
        int i = (bid - 12549) * 1024 + tid * 4;
        *reinterpret_cast<float4*>(psum + i) = (float4){0.f, 0.f, 0.f, 0.f};
    }
}

// ---------------- fused layer: agg (mean gather) + GEMM + bias + relu/pool ----------------
// 256-thread blocks, 4 waves; each wave owns 16 output rows + a private 4 KB LDS slab
// (no barriers anywhere).
// Agg = flat edge stream, 2-DEEP SOFTWARE-PIPELINED 16-edge chunks (r3 post-mortem:
// the single-buffered version serialized csr-wait -> gather-wait per chunk; the
// eager select of the prefetched csr word forced a vmcnt(0) before the gathers).
// Steady state per stage: issue 16 gathers for chunk c+1 (raw csr words loaded one
// full stage ago -> their wait is already satisfied), issue csr load for chunk c+2,
// accumulate chunk c (its gathers have had a full stage to land). ~33 loads in
// flight per wave; padded lanes gather the L1-resident all-zero row N_NODES.
// Named vA/vB buffers, fully unrolled: all register indexing compile-time.
// mode: 0 = plain store, 1 = relu store, 2 = pooled (atomicAdd per-graph sums).
__global__ void __launch_bounds__(256, 6) layer_kernel(
    const unsigned short* __restrict__ hin,   // N_NODES+1 rows; row N_NODES is zero
    const int* __restrict__ rowptr, const int* __restrict__ csr,
    const unsigned short* __restrict__ frag, const float* __restrict__ bias,
    unsigned short* __restrict__ hout,
    const int* __restrict__ batch, float* __restrict__ psum, int mode)
{
    __shared__ __attribute__((aligned(16))) unsigned short As[4][16 * DCH];  // 16 KB
    const int wave = threadIdx.x >> 6;
    const int lane = threadIdx.x & 63;
    const int l16  = lane & 15;
    const int quad = lane >> 4;
    const int base = blockIdx.x * 64 + wave * 16;
    if (base >= N_NODES) return;             // no barriers in kernel: early-out safe

    char* Asb = reinterpret_cast<char*>(As[wave]);

    // rowptr[base .. base+16]: one coalesced load; readlane thereafter (SGPR)
    int ridx = base + (lane < 17 ? lane : 16);
    if (ridx > N_NODES) ridx = N_NODES;
    int rp = rowptr[ridx];
    const int R0 = __builtin_amdgcn_readlane(rp, 0);
    const int R1 = __builtin_amdgcn_readlane(rp, 16);

    int ni     = 0;                          // current node (0..15), scalar
    int nstart = R0;
    int nend   = __builtin_amdgcn_readlane(rp, 1);
    float a0 = 0.f, a1 = 0.f;

    // chunk count, padded to even (padded edges gather the zero row)
    int nch = (R1 - R0 + 15) >> 4;
    if (nch < 1) nch = 1;
    const int nch2 = (nch + 1) & ~1;

    unsigned vA[16], vB[16];

    // prologue: chunk 0 gathers into vA; chunk 1 raw csr into tB
    int tA = csr[R0 + l16];
    int tB;
    {
        int idx = (R0 + l16 < R1) ? tA : N_NODES;
        #pragma unroll
        for (int j = 0; j < 16; j++) {
            int s = __builtin_amdgcn_readlane(idx, j);
            vA[j] = *reinterpret_cast<const unsigned*>(hin + (size_t)s * DCH + lane * 2);
        }
        tB = csr[R0 + 16 + l16];
    }

    int e0 = R0;
    for (int c = 0; c < nch2; c += 2) {
        // ---- stage A: issue gathers for chunk c+1 (from tB), accumulate vA (chunk c)
        {
            int e1 = e0 + 16;
            int idx = (e1 + l16 < R1) ? tB : N_NODES;    // tB loaded one full stage ago
            #pragma unroll
            for (int j = 0; j < 16; j++) {
                int s = __builtin_amdgcn_readlane(idx, j);
                vB[j] = *reinterpret_cast<const unsigned*>(hin + (size_t)s * DCH + lane * 2);
            }
            tA = csr[e0 + 32 + l16];                     // raw csr for chunk c+2
            #pragma unroll
            for (int j = 0; j < 16; j++) {
                int e = e0 + j;                          // uniform
                while (ni < 16 && e == nend) {           // finalize node ni
                    int deg = nend - nstart;
                    float inv = 1.0f / (float)(deg > 1 ? deg : 1);
                    unsigned o = ((unsigned)f2bf(a1 * inv) << 16) | (unsigned)f2bf(a0 * inv);
                    *reinterpret_cast<unsigned*>(Asb + ni * 256 + ((lane * 4) ^ ((ni & 7) << 4))) = o;
                    a0 = 0.f; a1 = 0.f;
                    ni++;
                    nstart = nend;
                    nend = __builtin_amdgcn_readlane(rp, ni + 1 < 17 ? ni + 1 : 16);
                }
                a0 += bf2f((unsigned short)(vA[j] & 0xffffu));
                a1 += bf2f((unsigned short)(vA[j] >> 16));
            }
            e0 = e1;
        }
        // ---- stage B: issue gathers for chunk c+2 (from tA), accumulate vB (chunk c+1)
        {
            int e1 = e0 + 16;
            int idx = (e1 + l16 < R1) ? tA : N_NODES;
            #pragma unroll
            for (int j = 0; j < 16; j++) {
                int s = __builtin_amdgcn_readlane(idx, j);
                vA[j] = *reinterpret_cast<const unsigned*>(hin + (size_t)s * DCH + lane * 2);
            }
            tB = csr[e0 + 32 + l16];                     // raw csr for chunk c+3
            #pragma unroll
            for (int j = 0; j < 16; j++) {
                int e = e0 + j;
                while (ni < 16 && e == nend) {
                    int deg = nend - nstart;
                    float inv = 1.0f / (float)(deg > 1 ? deg : 1);
                    unsigned o = ((unsigned)f2bf(a1 * inv) << 16) | (unsigned)f2bf(a0 * inv);
                    *reinterpret_cast<unsigned*>(Asb + ni * 256 + ((lane * 4) ^ ((ni & 7) << 4))) = o;
                    a0 = 0.f; a1 = 0.f;
                    ni++;
                    nstart = nend;
                    nend = __builtin_amdgcn_readlane(rp, ni + 1 < 17 ? ni + 1 : 16);
                }
                a0 += bf2f((unsigned short)(vB[j] & 0xffffu));
                a1 += bf2f((unsigned short)(vB[j] >> 16));
            }
            e0 = e1;
        }
    }
    while (ni < 16) {                        // finalize tail (incl. zero-degree nodes)
        int deg = nend - nstart;
        float inv = 1.0f / (float)(deg > 1 ? deg : 1);
        unsigned o = ((unsigned)f2bf(a1 * inv) << 16) | (unsigned)f2bf(a0 * inv);
        *reinterpret_cast<unsigned*>(Asb + ni * 256 + ((lane * 4) ^ ((ni & 7) << 4))) = o;
        a0 = 0.f; a1 = 0.f;
        ni++;
        nstart = nend;
        nend = __builtin_amdgcn_readlane(rp, ni + 1 < 17 ? ni + 1 : 16);
    }
    // wave-private LDS: compiler lgkmcnt covers write->read dep; no barrier.

    // ---------- MFMA: M=16 tile, [agg | root] @ [Wrel; Wroot] ----------
    v4f acc[8];
    #pragma unroll
    for (int nt = 0; nt < 8; nt++) acc[nt] = (v4f){0.f, 0.f, 0.f, 0.f};

    #pragma unroll
    for (int kt = 0; kt < 8; kt++) {
        v8s av;
        if (kt < 4) {
            int co = (kt * 64 + quad * 16) ^ ((l16 & 7) << 4);
            av = *reinterpret_cast<const v8s*>(Asb + l16 * 256 + co);
        } else {
            int ak = (kt - 4) * 32 + quad * 8;
            int row = base + l16; if (row > N_NODES) row = N_NODES;
            av = *reinterpret_cast<const v8s*>(hin + (size_t)row * DCH + ak);
        }
        #pragma unroll
        for (int nt = 0; nt < 8; nt++) {
            v8s b = *reinterpret_cast<const v8s*>(frag + (((size_t)(kt * 8 + nt)) * 64 + lane) * 8);
            acc[nt] = __builtin_amdgcn_mfma_f32_16x16x32_bf16(av, b, acc[nt], 0, 0, 0);
        }
    }

    if (mode != 2) {
        #pragma unroll
        for (int nt = 0; nt < 8; nt++) {
            int n = nt * 16 + l16;
            float bv = bias[n];
            #pragma unroll
            for (int r = 0; r < 4; r++) {
                int row = base + quad * 4 + r;
                if (row < N_NODES) {
                    float v = acc[nt][r] + bv;
                    if (mode == 1) v = fmaxf(v, 0.f);
                    hout[(size_t)row * DCH + n] = f2bf(v);
                }
            }
        }
    } else {
        // pooled epilogue: per-graph sums (mean + matvec applied in final_kernel)
        int last = base + 15;
        bool fast = (last < N_NODES) && (batch[base] == batch[last]);
        if (fast) {
            int g = batch[base];             // all 16 rows same graph (~94% of waves)
            #pragma unroll
            for (int nt = 0; nt < 8; nt++) {
                int n = nt * 16 + l16;
                float s = acc[nt][0] + acc[nt][1] + acc[nt][2] + acc[nt][3] + 4.0f * bias[n];
                s += __shfl_xor(s, 16);      // reduce across quads (rows)
                s += __shfl_xor(s, 32);
                if (quad == 0) atomicAdd(&psum[g * DCH + n], s);
            }
        } else {
            int g[4];
            #pragma unroll
            for (int r = 0; r < 4; r++) {
                int row = base + quad * 4 + r;
                g[r] = (row < N_NODES) ? batch[row] : -1;
            }
            #pragma unroll
            for (int nt = 0; nt < 8; nt++) {
                int n = nt * 16 + l16;
                float bv = bias[n];
                float s = 0.f; int cg = -1;
                #pragma unroll
                for (int r = 0; r < 4; r++) {
                    if (g[r] < 0) continue;
                    if (g[r] != cg) {
                        if (cg >= 0) atomicAdd(&psum[cg * DCH + n], s);
                        s = 0.f; cg = g[r];
                    }
                    s += acc[nt][r] + bv;
                }
                if (cg >= 0) atomicAdd(&psum[cg * DCH + n], s);
            }
        }
    }
}

// ---------------- final: out[g] = (psum[g]/cnt_g) @ Wl + bl ----------------
static __device__ __forceinline__ int lowerb(const int* __restrict__ a, int n, int key) {
    int lo = 0, hi = n;
    while (lo < hi) { int mid = (lo + hi) >> 1; if (a[mid] < key) lo = mid + 1; else hi = mid; }
    return lo;
}

__global__ void __launch_bounds__(64) final_kernel(const float* __restrict__ psum,
                                                   const int* __restrict__ batch,
                                                   const float* __restrict__ Wl, const float* __restrict__ bl,
                                                   float* __restrict__ out) {
    __shared__ float ps[DCH];
    __shared__ int bounds[2];
    int g = blockIdx.x, tid = threadIdx.x;
    if (tid == 0) {
        bounds[0] = lowerb(batch, N_NODES, g);
        bounds[1] = lowerb(batch, N_NODES, g + 1);
    }
    __syncthreads();
    int cnt = bounds[1] - bounds[0];
    float inv = 1.0f / (float)(cnt > 1 ? cnt : 1);
    ps[tid] = psum[g * DCH + tid] * inv;
    ps[tid + 64] = psum[g * DCH + tid + 64] * inv;
    __syncthreads();
    float o = 0.f;
    #pragma unroll 4
    for (int c = 0; c < DCH; c++) o += ps[c] * Wl[c * DOUT + tid];
    out[g * DOUT + tid] = o + bl[tid];
}

extern "C" void kernel_launch(void* const* d_in, const int* in_sizes, int n_in,
                              void* d_out, int out_size, void* d_ws, size_t ws_size,
                              hipStream_t stream) {
    const float* x     = (const float*)d_in[0];
    const int*   edge  = (const int*)d_in[1];
    const int*   src   = edge;
    const int*   dst   = edge + N_EDGES;
    const int*   batch = (const int*)d_in[2];
    const float* W1rel  = (const float*)d_in[3];
    const float* b1     = (const float*)d_in[4];
    const float* W1root = (const float*)d_in[5];
    const float* W2rel  = (const float*)d_in[6];
    const float* b2     = (const float*)d_in[7];
    const float* W2root = (const float*)d_in[8];
    const float* W3rel  = (const float*)d_in[9];
    const float* b3     = (const float*)d_in[10];
    const float* W3root = (const float*)d_in[11];
    const float* Wl     = (const float*)d_in[12];
    const float* bl     = (const float*)d_in[13];
    float* out = (float*)d_out;

    char* ws = (char*)d_ws;
    size_t off = 0;
    auto carve = [&](size_t bytes) -> void* {
        void* p = ws + off;
        off += (bytes + 255) & ~(size_t)255;
        return p;
    };
    int*            rowptr  = (int*)carve((size_t)(N_NODES + 1) * 4);
    int*            csr     = (int*)carve((size_t)(N_EDGES + 128) * 4);  // +128: pipelined prefetch slack
    int*            gcur    = (int*)carve((size_t)PADB * 4 + (size_t)N_GRAPHS * DCH * 4); // gcur + psum
    float*          psum    = (float*)(gcur + PADB);
    int*            hoffG   = (int*)carve((size_t)PADB * 4);
    unsigned short* frag    = (unsigned short*)carve((size_t)3 * 8 * 8 * 64 * 8 * 2);
    unsigned short* B1      = (unsigned short*)carve((size_t)(N_NODES + 1) * DCH * 2);   // +1 zero row
    unsigned short* B2      = (unsigned short*)carve((size_t)(N_NODES + 1) * DCH * 2);   // +1 zero row
    uint2*          region  = (uint2*)B1;   // 391*4608*8 = 14.4 MB <= 25.6 MB (zero row beyond region)

    // prep first: cvt + frags + zero rows + gcur/psum clear (replaces hipMemsetAsync)
    prep_kernel<<<12581, 256, 0, stream>>>(x, B2, W1rel, W1root, W2rel, W2root, W3rel, W3root,
                                           frag, B1 + (size_t)N_NODES * DCH, B2 + (size_t)N_NODES * DCH,
                                           gcur, psum);

    // CSR build: binA -> scan -> binFinish
    binA_kernel<<<(N_EDGES + CHUNK - 1) / CHUNK, 256, 0, stream>>>(src, dst, gcur, region);
    scan_kernel<<<1, 256, 0, stream>>>(gcur, hoffG, rowptr);
    binFinish_kernel<<<NB, 256, 0, stream>>>(region, gcur, hoffG, rowptr, csr);

    const int layerGrid = (N_NODES + 63) / 64;   // 1563 blocks x 4 waves x 16 rows

    // fused layers; ping-pong B2 -> B1 -> B2; layer 3 pools directly into psum
    layer_kernel<<<layerGrid, 256, 0, stream>>>(B2, rowptr, csr, frag,         b1, B1, batch, psum, 1);
    layer_kernel<<<layerGrid, 256, 0, stream>>>(B1, rowptr, csr, frag + 32768, b2, B2, batch, psum, 1);
    layer_kernel<<<layerGrid, 256, 0, stream>>>(B2, rowptr, csr, frag + 65536, b3, B1, batch, psum, 2);

    final_kernel<<<N_GRAPHS, 64, 0, stream>>>(psum, batch, Wl, bl, out);
}